// Round 6
// baseline (952.461 us; speedup 1.0000x reference)
//
#include <hip/hip_runtime.h>

typedef unsigned int uint32;
typedef unsigned short ushort16;
using short8 = __attribute__((ext_vector_type(8))) short;
using f32x4  = __attribute__((ext_vector_type(4))) float;

__device__ __forceinline__ float bfl(uint32 v) { return __uint_as_float(v << 16); }
__device__ __forceinline__ float bfh(uint32 v) { return __uint_as_float(v & 0xffff0000u); }
__device__ __forceinline__ ushort16 f2bf(float f) {
    uint32 u = __float_as_uint(f);
    u += 0x7fffu + ((u >> 16) & 1u);   // RNE
    return (ushort16)(u >> 16);
}
__device__ __forceinline__ uint32 pack2(float x, float y) {
    return (uint32)f2bf(x) | ((uint32)f2bf(y) << 16);
}

constexpr int BSH = 6;   // 64 nodes per bucket

// ---------------- CSR build (bucketed counting sort) ----------------

__global__ void zero_int_kernel(int* __restrict__ p, int n) {
    int i = blockIdx.x * blockDim.x + threadIdx.x;
    if (i < n) p[i] = 0;
}

// count edges per bucket (bucket = global_dst >> BSH)
__global__ void bucket_count_kernel(const int* __restrict__ d0, const int* __restrict__ d1,
                                    const int* __restrict__ d2, int e0, int e01, int e012,
                                    int o1, int o2, int* __restrict__ bcnt) {
    int i = blockIdx.x * blockDim.x + threadIdx.x;
    int g;
    if (i < e0)        g = d0[i];
    else if (i < e01)  g = o1 + d1[i - e0];
    else if (i < e012) g = o2 + d2[i - e01];
    else return;
    atomicAdd(&bcnt[g >> BSH], 1);
}

// scatter (g_dst, src) pairs into bucket segments (write frontier = nbuckets lines, L2-hot)
__global__ void bucket_scatter_kernel(const int* __restrict__ s0, const int* __restrict__ d0,
                                      const int* __restrict__ s1, const int* __restrict__ d1,
                                      const int* __restrict__ s2, const int* __restrict__ d2,
                                      int e0, int e01, int e012, int o1, int o2,
                                      const int* __restrict__ bofs, int* __restrict__ bcur,
                                      uint2* __restrict__ bpair) {
    int i = blockIdx.x * blockDim.x + threadIdx.x;
    int g, sv;
    if (i < e0)        { g = d0[i];            sv = s0[i]; }
    else if (i < e01)  { g = o1 + d1[i - e0];  sv = s1[i - e0]; }
    else if (i < e012) { g = o2 + d2[i - e01]; sv = s2[i - e01]; }
    else return;
    int b = g >> BSH;
    int p = atomicAdd(&bcur[b], 1);
    bpair[bofs[b] + p] = make_uint2((uint32)g, (uint32)sv);
}

// per-bucket degree histogram: atomics confined to a 64-node (256 B) region
__global__ __launch_bounds__(256) void bucket_deg_kernel(const uint2* __restrict__ bpair,
                                                         const int* __restrict__ bofs,
                                                         int* __restrict__ deg) {
    int lo = bofs[blockIdx.x], hi = bofs[blockIdx.x + 1];
    for (int i = lo + threadIdx.x; i < hi; i += 256)
        atomicAdd(&deg[bpair[i].x], 1);
}

// per-bucket scatter into esrc: target region ~3 KB contiguous, L2-hot, lines fully covered
__global__ __launch_bounds__(256) void bucket_esrc_kernel(const uint2* __restrict__ bpair,
                                                          const int* __restrict__ bofs,
                                                          const int* __restrict__ rs,
                                                          int* __restrict__ cur,
                                                          int* __restrict__ esrc) {
    int lo = bofs[blockIdx.x], hi = bofs[blockIdx.x + 1];
    for (int i = lo + threadIdx.x; i < hi; i += 256) {
        uint2 p = bpair[i];
        int q = atomicAdd(&cur[p.x], 1);
        esrc[rs[p.x] + q] = (int)p.y;
    }
}

// ---- generic 3-kernel exclusive scan ----
constexpr int SCAN_TPB = 256;
constexpr int SCAN_VPT = 4;
constexpr int SCAN_EPB = SCAN_TPB * SCAN_VPT;  // 1024

__global__ __launch_bounds__(SCAN_TPB) void scan_partial_kernel(const int* __restrict__ deg,
                                                                int n, int* __restrict__ partials) {
    __shared__ int red[SCAN_TPB];
    int t = threadIdx.x;
    int base = blockIdx.x * SCAN_EPB + t * SCAN_VPT;
    int s = 0;
    #pragma unroll
    for (int j = 0; j < SCAN_VPT; ++j) {
        int i = base + j;
        if (i < n) s += deg[i];
    }
    red[t] = s;
    __syncthreads();
    for (int off = SCAN_TPB / 2; off > 0; off >>= 1) {
        if (t < off) red[t] += red[t + off];
        __syncthreads();
    }
    if (t == 0) partials[blockIdx.x] = red[0];
}

__global__ __launch_bounds__(64) void scan_partials_kernel(int* __restrict__ partials, int nb,
                                                           int* __restrict__ total_out) {
    int lane = threadIdx.x;
    int run = 0;
    for (int base = 0; base < nb; base += 64) {
        int i = base + lane;
        int orig = (i < nb) ? partials[i] : 0;
        int v = orig;
        #pragma unroll
        for (int off = 1; off < 64; off <<= 1) {
            int u = __shfl_up(v, off);
            if (lane >= off) v += u;
        }
        if (i < nb) partials[i] = run + (v - orig);
        run += __shfl(v, 63);
    }
    if (lane == 0) *total_out = run;
}

__global__ __launch_bounds__(SCAN_TPB) void scan_final_kernel(const int* __restrict__ deg, int n,
                                                              const int* __restrict__ partials,
                                                              int* __restrict__ rs) {
    __shared__ int tsum[SCAN_TPB];
    int t = threadIdx.x;
    int base = blockIdx.x * SCAN_EPB + t * SCAN_VPT;
    int v[SCAN_VPT];
    int s = 0;
    #pragma unroll
    for (int j = 0; j < SCAN_VPT; ++j) {
        int i = base + j;
        v[j] = (i < n) ? deg[i] : 0;
        s += v[j];
    }
    tsum[t] = s;
    __syncthreads();
    for (int off = 1; off < SCAN_TPB; off <<= 1) {
        int add = (t >= off) ? tsum[t - off] : 0;
        __syncthreads();
        tsum[t] += add;
        __syncthreads();
    }
    int run = partials[blockIdx.x] + (t ? tsum[t - 1] : 0);
    #pragma unroll
    for (int j = 0; j < SCAN_VPT; ++j) {
        int i = base + j;
        if (i < n) rs[i] = run;
        run += v[j];
    }
}

// ---------------- conversions (fused) ----------------

__global__ void cvt_x2_kernel(const float* __restrict__ a, int n4a,
                              const float* __restrict__ b, int n4b,
                              uint32* __restrict__ oa, uint32* __restrict__ ob) {
    int i = blockIdx.x * blockDim.x + threadIdx.x;
    if (i < n4a) {
        float4 v = ((const float4*)a)[i];
        ((uint2*)oa)[i] = make_uint2(pack2(v.x, v.y), pack2(v.z, v.w));
    } else if (i < n4a + n4b) {
        int j = i - n4a;
        float4 v = ((const float4*)b)[j];
        ((uint2*)ob)[j] = make_uint2(pack2(v.x, v.y), pack2(v.z, v.w));
    }
}

struct CvtWArgs { const float* W[6]; ushort16* Wt[6]; };

__global__ void cvtW_all_kernel(CvtWArgs a) {
    int i = blockIdx.x * blockDim.x + threadIdx.x;
    if (i < 3 * 16384) {
        int m = i / 16384, idx = i % 16384;
        int n = idx >> 7, k = idx & 127;
        a.Wt[m][n * 128 + k] = f2bf(a.W[m][k * 128 + n]);
    } else {
        i -= 3 * 16384;
        if (i >= 3 * 8192) return;
        int m = 3 + i / 8192, idx = i % 8192;
        int n = idx >> 7, k = idx & 127;
        a.Wt[m][n * 128 + k] = f2bf(a.W[m][k * 64 + n]);
    }
}

// ---------------- MFMA GEMM: Y[N x M](bf16) = X[N x 128](bf16) @ Wt[n][k] ----------------

template<int M>  // 128 or 64
__global__ __launch_bounds__(256) void gemm_bf16_kernel(const ushort16* __restrict__ X,
                                                        const ushort16* __restrict__ Wt,
                                                        ushort16* __restrict__ Y, int N) {
    constexpr int NTW = M / 64;
    const int w = threadIdx.x >> 6;
    const int l = threadIdx.x & 63;
    const int lr = l & 15, lg = l >> 4;
    const int row0 = blockIdx.x * 16;
    if (row0 >= N) return;

    const ushort16* xr = X + (size_t)(row0 + lr) * 128 + lg * 8;
    short8 a[4];
    #pragma unroll
    for (int ks = 0; ks < 4; ++ks) a[ks] = *(const short8*)(xr + ks * 32);

    f32x4 acc[NTW];
    #pragma unroll
    for (int t = 0; t < NTW; ++t) acc[t] = (f32x4){0.f, 0.f, 0.f, 0.f};

    #pragma unroll
    for (int t = 0; t < NTW; ++t) {
        int n = w * (NTW * 16) + t * 16 + lr;
        const ushort16* wr = Wt + (size_t)n * 128 + lg * 8;
        #pragma unroll
        for (int ks = 0; ks < 4; ++ks) {
            short8 b = *(const short8*)(wr + ks * 32);
            acc[t] = __builtin_amdgcn_mfma_f32_16x16x32_bf16(a[ks], b, acc[t], 0, 0, 0);
        }
    }

    #pragma unroll
    for (int t = 0; t < NTW; ++t) {
        int col = w * (NTW * 16) + t * 16 + lr;
        #pragma unroll
        for (int j = 0; j < 4; ++j) {
            int r = row0 + lg * 4 + j;
            Y[(size_t)r * M + col] = f2bf(acc[t][j]);
        }
    }
}

// ---------------- Aggregation (bf16 table, high-MLP, LDS-staged indices) ----------------

// D=128: half-wave per edge, uint2/lane, unroll 2 -> 4 gathers in flight
template<bool ACCUM>
__global__ __launch_bounds__(256) void agg128_bf16_kernel(const ushort16* __restrict__ t,
                                                          const int* __restrict__ esrc,
                                                          const int* __restrict__ rs,
                                                          const float* __restrict__ bias,
                                                          uint32* __restrict__ out, int n) {
    __shared__ int sidx[4][64];
    int w = threadIdx.x >> 6;
    int lane = threadIdx.x & 63;
    int wid = blockIdx.x * 4 + w;
    if (wid >= n) return;
    int e0 = rs[wid], e1 = rs[wid + 1];
    int h = lane >> 5, c = lane & 31;
    const uint2* tb = (const uint2*)t;    // row = 32 uint2 (256 B)
    float ax = 0.f, ay = 0.f, az = 0.f, aw = 0.f;
    for (int base = e0; base < e1; base += 64) {
        int cnt = min(64, e1 - base);
        if (lane < cnt) sidx[w][lane] = esrc[base + lane];  // wave-local: no barrier
        int j = h;
        for (; j + 2 < cnt; j += 4) {
            int i0 = sidx[w][j];
            int i1 = sidx[w][j + 2];
            uint2 v0 = tb[(size_t)i0 * 32 + c];
            uint2 v1 = tb[(size_t)i1 * 32 + c];
            ax += bfl(v0.x) + bfl(v1.x);  ay += bfh(v0.x) + bfh(v1.x);
            az += bfl(v0.y) + bfl(v1.y);  aw += bfh(v0.y) + bfh(v1.y);
        }
        if (j < cnt) {
            int i0 = sidx[w][j];
            uint2 v0 = tb[(size_t)i0 * 32 + c];
            ax += bfl(v0.x); ay += bfh(v0.x); az += bfl(v0.y); aw += bfh(v0.y);
        }
    }
    ax += __shfl_xor(ax, 32); ay += __shfl_xor(ay, 32);
    az += __shfl_xor(az, 32); aw += __shfl_xor(aw, 32);
    if (lane < 32) {
        float inv = 1.f / (float)max(e1 - e0, 1);
        float4 bv = ((const float4*)bias)[c];
        float rx = ax * inv + bv.x, ry = ay * inv + bv.y;
        float rz = az * inv + bv.z, rw = aw * inv + bv.w;
        uint2* op = (uint2*)out + (size_t)wid * 32 + c;
        if (ACCUM) {
            uint2 old = *op;
            rx += bfl(old.x); ry += bfh(old.x); rz += bfl(old.y); rw += bfh(old.y);
        }
        *op = make_uint2(pack2(rx, ry), pack2(rz, rw));
    }
}

// D=64: quarter-wave per edge, uint2/lane, unroll 2 -> 8 gathers in flight
template<bool ACCUM>
__global__ __launch_bounds__(256) void agg64_bf16_kernel(const ushort16* __restrict__ t,
                                                         const int* __restrict__ esrc,
                                                         const int* __restrict__ rs,
                                                         const float* __restrict__ bias,
                                                         float* __restrict__ out, int n) {
    __shared__ int sidx[4][64];
    int w = threadIdx.x >> 6;
    int lane = threadIdx.x & 63;
    int wid = blockIdx.x * 4 + w;
    if (wid >= n) return;
    int e0 = rs[wid], e1 = rs[wid + 1];
    int q = lane >> 4, c = lane & 15;
    const uint2* tb = (const uint2*)t;    // row = 16 uint2 (128 B)
    float ax = 0.f, ay = 0.f, az = 0.f, aw = 0.f;
    for (int base = e0; base < e1; base += 64) {
        int cnt = min(64, e1 - base);
        if (lane < cnt) sidx[w][lane] = esrc[base + lane];
        int j = q;
        for (; j + 4 < cnt; j += 8) {
            int i0 = sidx[w][j];
            int i1 = sidx[w][j + 4];
            uint2 v0 = tb[(size_t)i0 * 16 + c];
            uint2 v1 = tb[(size_t)i1 * 16 + c];
            ax += bfl(v0.x) + bfl(v1.x);  ay += bfh(v0.x) + bfh(v1.x);
            az += bfl(v0.y) + bfl(v1.y);  aw += bfh(v0.y) + bfh(v1.y);
        }
        if (j < cnt) {
            int i0 = sidx[w][j];
            uint2 v0 = tb[(size_t)i0 * 16 + c];
            ax += bfl(v0.x); ay += bfh(v0.x); az += bfl(v0.y); aw += bfh(v0.y);
        }
    }
    ax += __shfl_xor(ax, 16); ay += __shfl_xor(ay, 16);
    az += __shfl_xor(az, 16); aw += __shfl_xor(aw, 16);
    ax += __shfl_xor(ax, 32); ay += __shfl_xor(ay, 32);
    az += __shfl_xor(az, 32); aw += __shfl_xor(aw, 32);
    if (lane < 16) {
        float inv = 1.f / (float)max(e1 - e0, 1);
        float4 bv = ((const float4*)bias)[c];
        float4 r;
        r.x = ax * inv + bv.x; r.y = ay * inv + bv.y;
        r.z = az * inv + bv.z; r.w = aw * inv + bv.w;
        float4* op = (float4*)out + (size_t)wid * 16 + c;
        if (ACCUM) { float4 o = *op; r.x += o.x; r.y += o.y; r.z += o.z; r.w += o.w; }
        *op = r;
    }
}

// ---------------- launch ----------------

extern "C" void kernel_launch(void* const* d_in, const int* in_sizes, int n_in,
                              void* d_out, int out_size, void* d_ws, size_t ws_size,
                              hipStream_t stream) {
    const float* x_drug = (const float*)d_in[0];
    const float* x_prot = (const float*)d_in[1];
    const int* src[3] = { (const int*)d_in[2], (const int*)d_in[4], (const int*)d_in[6] };
    const int* dst[3] = { (const int*)d_in[3], (const int*)d_in[5], (const int*)d_in[7] };
    const float* W1[3] = { (const float*)d_in[8],  (const float*)d_in[10], (const float*)d_in[12] };
    const float* b1[3] = { (const float*)d_in[9],  (const float*)d_in[11], (const float*)d_in[13] };
    const float* W2[3] = { (const float*)d_in[14], (const float*)d_in[16], (const float*)d_in[18] };
    const float* b2[3] = { (const float*)d_in[15], (const float*)d_in[17], (const float*)d_in[19] };

    const int ND = in_sizes[0] / 128;
    const int NP = in_sizes[1] / 128;
    const int EC[3] = { in_sizes[2], in_sizes[4], in_sizes[6] };
    float* out = (float*)d_out;

    const int o1 = ND, o2 = ND + NP;
    const int TN = ND + 2 * NP;
    const int NB = (TN + (1 << BSH) - 1) >> BSH;
    const int e0c = EC[0], e01 = EC[0] + EC[1], e012 = EC[0] + EC[1] + EC[2];

    // workspace layout
    char* w = (char*)d_ws;
    const size_t maxN = (size_t)(ND > NP ? ND : NP);
    ushort16* xd16 = (ushort16*)w; w += (size_t)ND * 128 * 2;
    ushort16* xp16 = (ushort16*)w; w += (size_t)NP * 128 * 2;
    ushort16* hd16 = (ushort16*)w; w += (size_t)ND * 128 * 2;
    ushort16* hp16 = (ushort16*)w; w += (size_t)NP * 128 * 2;
    ushort16* tb16 = (ushort16*)w; w += maxN * 128 * 2;
    ushort16* Wt[6];
    for (int r = 0; r < 3; ++r) { Wt[r] = (ushort16*)w; w += 128 * 128 * 2; }
    for (int r = 0; r < 3; ++r) { Wt[3 + r] = (ushort16*)w; w += 64 * 128 * 2; }
    int* ip = (int*)w;
    int* deg_all  = ip; ip += TN;
    int* cur_all  = ip; ip += TN;
    int* bcnt     = ip; ip += NB;
    int* bcur     = ip; ip += NB;
    const int nzero = 2 * TN + 2 * NB;   // deg, cur, bcnt, bcur zeroed together
    int* rs_all   = ip; ip += TN + 1;
    int* bofs     = ip; ip += NB + 1;
    int* esrc_all = ip; ip += e012;
    int* parts    = ip; ip += 256;
    // bpair (14.4 MB) aliases hd16+hp16 (25.6 MB): dead once layer-1 agg starts
    uint2* bpair = (uint2*)hd16;

    const int* rsr[3] = { rs_all, rs_all + o1, rs_all + o2 };

    auto run_scan = [&](const int* in, int n, int* outp) {
        int nb = (n + SCAN_EPB - 1) / SCAN_EPB;
        scan_partial_kernel<<<nb, SCAN_TPB, 0, stream>>>(in, n, parts);
        scan_partials_kernel<<<1, 64, 0, stream>>>(parts, nb, outp + n);
        scan_final_kernel<<<nb, SCAN_TPB, 0, stream>>>(in, n, parts, outp);
    };

    // ---- conversions ----
    {
        int n4d = ND * 32, n4p = NP * 32;
        cvt_x2_kernel<<<(n4d + n4p + 255) / 256, 256, 0, stream>>>(x_drug, n4d, x_prot, n4p,
                                                                   (uint32*)xd16, (uint32*)xp16);
        CvtWArgs a;
        for (int r = 0; r < 3; ++r) { a.W[r] = W1[r]; a.W[3 + r] = W2[r]; }
        for (int r = 0; r < 6; ++r) a.Wt[r] = Wt[r];
        cvtW_all_kernel<<<(3 * 16384 + 3 * 8192 + 255) / 256, 256, 0, stream>>>(a);
    }

    // ---- CSR build (bucketed) ----
    zero_int_kernel<<<(nzero + 255) / 256, 256, 0, stream>>>(deg_all, nzero);
    bucket_count_kernel<<<(e012 + 255) / 256, 256, 0, stream>>>(dst[0], dst[1], dst[2],
                                                                e0c, e01, e012, o1, o2, bcnt);
    run_scan(bcnt, NB, bofs);
    bucket_scatter_kernel<<<(e012 + 255) / 256, 256, 0, stream>>>(src[0], dst[0], src[1], dst[1],
                                                                  src[2], dst[2], e0c, e01, e012,
                                                                  o1, o2, bofs, bcur, bpair);
    bucket_deg_kernel<<<NB, 256, 0, stream>>>(bpair, bofs, deg_all);
    run_scan(deg_all, TN, rs_all);
    bucket_esrc_kernel<<<NB, 256, 0, stream>>>(bpair, bofs, rs_all, cur_all, esrc_all);

    auto gblocks = [](int n) { return (n + 15) / 16; };
    auto ablocks = [](int n) { return (n + 3) / 4; };

    // ---- layer 1 ----
    gemm_bf16_kernel<128><<<gblocks(ND), 256, 0, stream>>>(xd16, Wt[0], tb16, ND);
    agg128_bf16_kernel<false><<<ablocks(ND), 256, 0, stream>>>(tb16, esrc_all, rsr[0], b1[0],
                                                               (uint32*)hd16, ND);
    gemm_bf16_kernel<128><<<gblocks(ND), 256, 0, stream>>>(xd16, Wt[1], tb16, ND);
    agg128_bf16_kernel<false><<<ablocks(NP), 256, 0, stream>>>(tb16, esrc_all, rsr[1], b1[1],
                                                               (uint32*)hp16, NP);
    gemm_bf16_kernel<128><<<gblocks(NP), 256, 0, stream>>>(xp16, Wt[2], tb16, NP);
    agg128_bf16_kernel<true><<<ablocks(NP), 256, 0, stream>>>(tb16, esrc_all, rsr[2], b1[2],
                                                              (uint32*)hp16, NP);

    // ---- layer 2 ----
    gemm_bf16_kernel<64><<<gblocks(ND), 256, 0, stream>>>(hd16, Wt[3], tb16, ND);
    agg64_bf16_kernel<false><<<ablocks(ND), 256, 0, stream>>>(tb16, esrc_all, rsr[0], b2[0],
                                                              out, ND);
    gemm_bf16_kernel<64><<<gblocks(ND), 256, 0, stream>>>(hd16, Wt[4], tb16, ND);
    agg64_bf16_kernel<false><<<ablocks(NP), 256, 0, stream>>>(tb16, esrc_all, rsr[1], b2[1],
                                                              out + (size_t)ND * 64, NP);
    gemm_bf16_kernel<64><<<gblocks(NP), 256, 0, stream>>>(hp16, Wt[5], tb16, NP);
    agg64_bf16_kernel<true><<<ablocks(NP), 256, 0, stream>>>(tb16, esrc_all, rsr[2], b2[2],
                                                             out + (size_t)ND * 64, NP);
}

// Round 7
// 460.379 us; speedup vs baseline: 2.0689x; 2.0689x over previous
//
#include <hip/hip_runtime.h>

typedef unsigned int uint32;
typedef unsigned short ushort16;
using short8 = __attribute__((ext_vector_type(8))) short;
using f32x4  = __attribute__((ext_vector_type(4))) float;

__device__ __forceinline__ float bfl(uint32 v) { return __uint_as_float(v << 16); }
__device__ __forceinline__ float bfh(uint32 v) { return __uint_as_float(v & 0xffff0000u); }
__device__ __forceinline__ ushort16 f2bf(float f) {
    uint32 u = __float_as_uint(f);
    u += 0x7fffu + ((u >> 16) & 1u);   // RNE
    return (ushort16)(u >> 16);
}
__device__ __forceinline__ uint32 pack2(float x, float y) {
    return (uint32)f2bf(x) | ((uint32)f2bf(y) << 16);
}

// ---------------- CSR build (XCD-sliced: each dst-slice written by one XCD) ----------------

__global__ void zero_int_kernel(int* __restrict__ p, int n) {
    int i = blockIdx.x * blockDim.x + threadIdx.x;
    if (i < n) p[i] = 0;
}

// blocks with blockIdx%8 == s handle dst-slice s (HW round-robins blocks over XCDs,
// so all appends to a slice come from one XCD's L2 -> no cross-XCD line ping-pong).
__global__ __launch_bounds__(256) void hist_sliced_kernel(
        const int* __restrict__ d0, const int* __restrict__ d1, const int* __restrict__ d2,
        int e0, int e01, int e012, int o1, int o2,
        int sl, int tn, int nbs, int* __restrict__ deg) {
    int s = blockIdx.x & 7;
    int bj = blockIdx.x >> 3;
    int lo = s * sl;
    int hi = min(lo + sl, tn);
    int stride = nbs * 256;
    for (int i = bj * 256 + threadIdx.x; i < e012; i += stride) {
        int g;
        if (i < e0)       g = d0[i];
        else if (i < e01) g = o1 + d1[i - e0];
        else              g = o2 + d2[i - e01];
        if (g >= lo && g < hi) atomicAdd(&deg[g], 1);
    }
}

__global__ __launch_bounds__(256) void scatter_sliced_kernel(
        const int* __restrict__ s0, const int* __restrict__ d0,
        const int* __restrict__ s1, const int* __restrict__ d1,
        const int* __restrict__ s2, const int* __restrict__ d2,
        int e0, int e01, int e012, int o1, int o2,
        int sl, int tn, int nbs,
        const int* __restrict__ rs, int* __restrict__ cur, int* __restrict__ esrc) {
    int s = blockIdx.x & 7;
    int bj = blockIdx.x >> 3;
    int lo = s * sl;
    int hi = min(lo + sl, tn);
    int stride = nbs * 256;
    for (int i = bj * 256 + threadIdx.x; i < e012; i += stride) {
        int g;
        if (i < e0)       g = d0[i];
        else if (i < e01) g = o1 + d1[i - e0];
        else              g = o2 + d2[i - e01];
        if (g >= lo && g < hi) {
            int sv = (i < e0) ? s0[i] : (i < e01 ? s1[i - e0] : s2[i - e01]);
            int p = atomicAdd(&cur[g], 1);
            esrc[rs[g] + p] = sv;
        }
    }
}

// ---- generic 3-kernel exclusive scan ----
constexpr int SCAN_TPB = 256;
constexpr int SCAN_VPT = 4;
constexpr int SCAN_EPB = SCAN_TPB * SCAN_VPT;  // 1024

__global__ __launch_bounds__(SCAN_TPB) void scan_partial_kernel(const int* __restrict__ deg,
                                                                int n, int* __restrict__ partials) {
    __shared__ int red[SCAN_TPB];
    int t = threadIdx.x;
    int base = blockIdx.x * SCAN_EPB + t * SCAN_VPT;
    int s = 0;
    #pragma unroll
    for (int j = 0; j < SCAN_VPT; ++j) {
        int i = base + j;
        if (i < n) s += deg[i];
    }
    red[t] = s;
    __syncthreads();
    for (int off = SCAN_TPB / 2; off > 0; off >>= 1) {
        if (t < off) red[t] += red[t + off];
        __syncthreads();
    }
    if (t == 0) partials[blockIdx.x] = red[0];
}

__global__ __launch_bounds__(64) void scan_partials_kernel(int* __restrict__ partials, int nb,
                                                           int* __restrict__ total_out) {
    int lane = threadIdx.x;
    int run = 0;
    for (int base = 0; base < nb; base += 64) {
        int i = base + lane;
        int orig = (i < nb) ? partials[i] : 0;
        int v = orig;
        #pragma unroll
        for (int off = 1; off < 64; off <<= 1) {
            int u = __shfl_up(v, off);
            if (lane >= off) v += u;
        }
        if (i < nb) partials[i] = run + (v - orig);
        run += __shfl(v, 63);
    }
    if (lane == 0) *total_out = run;
}

__global__ __launch_bounds__(SCAN_TPB) void scan_final_kernel(const int* __restrict__ deg, int n,
                                                              const int* __restrict__ partials,
                                                              int* __restrict__ rs) {
    __shared__ int tsum[SCAN_TPB];
    int t = threadIdx.x;
    int base = blockIdx.x * SCAN_EPB + t * SCAN_VPT;
    int v[SCAN_VPT];
    int s = 0;
    #pragma unroll
    for (int j = 0; j < SCAN_VPT; ++j) {
        int i = base + j;
        v[j] = (i < n) ? deg[i] : 0;
        s += v[j];
    }
    tsum[t] = s;
    __syncthreads();
    for (int off = 1; off < SCAN_TPB; off <<= 1) {
        int add = (t >= off) ? tsum[t - off] : 0;
        __syncthreads();
        tsum[t] += add;
        __syncthreads();
    }
    int run = partials[blockIdx.x] + (t ? tsum[t - 1] : 0);
    #pragma unroll
    for (int j = 0; j < SCAN_VPT; ++j) {
        int i = base + j;
        if (i < n) rs[i] = run;
        run += v[j];
    }
}

// ---------------- conversions (fused) ----------------

__global__ void cvt_x2_kernel(const float* __restrict__ a, int n4a,
                              const float* __restrict__ b, int n4b,
                              uint32* __restrict__ oa, uint32* __restrict__ ob) {
    int i = blockIdx.x * blockDim.x + threadIdx.x;
    if (i < n4a) {
        float4 v = ((const float4*)a)[i];
        ((uint2*)oa)[i] = make_uint2(pack2(v.x, v.y), pack2(v.z, v.w));
    } else if (i < n4a + n4b) {
        int j = i - n4a;
        float4 v = ((const float4*)b)[j];
        ((uint2*)ob)[j] = make_uint2(pack2(v.x, v.y), pack2(v.z, v.w));
    }
}

struct CvtWArgs { const float* W[6]; ushort16* Wt[6]; };

__global__ void cvtW_all_kernel(CvtWArgs a) {
    int i = blockIdx.x * blockDim.x + threadIdx.x;
    if (i < 3 * 16384) {
        int m = i / 16384, idx = i % 16384;
        int n = idx >> 7, k = idx & 127;
        a.Wt[m][n * 128 + k] = f2bf(a.W[m][k * 128 + n]);
    } else {
        i -= 3 * 16384;
        if (i >= 3 * 8192) return;
        int m = 3 + i / 8192, idx = i % 8192;
        int n = idx >> 7, k = idx & 127;
        a.Wt[m][n * 128 + k] = f2bf(a.W[m][k * 64 + n]);
    }
}

// ---------------- MFMA GEMM: Y[N x M](bf16) = X[N x 128](bf16) @ Wt[n][k] ----------------

template<int M>  // 128 or 64
__global__ __launch_bounds__(256) void gemm_bf16_kernel(const ushort16* __restrict__ X,
                                                        const ushort16* __restrict__ Wt,
                                                        ushort16* __restrict__ Y, int N) {
    constexpr int NTW = M / 64;
    const int w = threadIdx.x >> 6;
    const int l = threadIdx.x & 63;
    const int lr = l & 15, lg = l >> 4;
    const int row0 = blockIdx.x * 16;
    if (row0 >= N) return;

    const ushort16* xr = X + (size_t)(row0 + lr) * 128 + lg * 8;
    short8 a[4];
    #pragma unroll
    for (int ks = 0; ks < 4; ++ks) a[ks] = *(const short8*)(xr + ks * 32);

    f32x4 acc[NTW];
    #pragma unroll
    for (int t = 0; t < NTW; ++t) acc[t] = (f32x4){0.f, 0.f, 0.f, 0.f};

    #pragma unroll
    for (int t = 0; t < NTW; ++t) {
        int n = w * (NTW * 16) + t * 16 + lr;
        const ushort16* wr = Wt + (size_t)n * 128 + lg * 8;
        #pragma unroll
        for (int ks = 0; ks < 4; ++ks) {
            short8 b = *(const short8*)(wr + ks * 32);
            acc[t] = __builtin_amdgcn_mfma_f32_16x16x32_bf16(a[ks], b, acc[t], 0, 0, 0);
        }
    }

    #pragma unroll
    for (int t = 0; t < NTW; ++t) {
        int col = w * (NTW * 16) + t * 16 + lr;
        #pragma unroll
        for (int j = 0; j < 4; ++j) {
            int r = row0 + lg * 4 + j;
            Y[(size_t)r * M + col] = f2bf(acc[t][j]);
        }
    }
}

// ---------------- Aggregation (bf16 table, high-MLP, LDS-staged indices) ----------------

// D=128: half-wave per edge, uint2/lane, unroll 2 -> 4 gathers in flight
template<bool ACCUM>
__global__ __launch_bounds__(256) void agg128_bf16_kernel(const ushort16* __restrict__ t,
                                                          const int* __restrict__ esrc,
                                                          const int* __restrict__ rs,
                                                          const float* __restrict__ bias,
                                                          uint32* __restrict__ out, int n) {
    __shared__ int sidx[4][64];
    int w = threadIdx.x >> 6;
    int lane = threadIdx.x & 63;
    int wid = blockIdx.x * 4 + w;
    if (wid >= n) return;
    int e0 = rs[wid], e1 = rs[wid + 1];
    int h = lane >> 5, c = lane & 31;
    const uint2* tb = (const uint2*)t;    // row = 32 uint2 (256 B)
    float ax = 0.f, ay = 0.f, az = 0.f, aw = 0.f;
    for (int base = e0; base < e1; base += 64) {
        int cnt = min(64, e1 - base);
        if (lane < cnt) sidx[w][lane] = esrc[base + lane];  // wave-local: no barrier
        int j = h;
        for (; j + 2 < cnt; j += 4) {
            int i0 = sidx[w][j];
            int i1 = sidx[w][j + 2];
            uint2 v0 = tb[(size_t)i0 * 32 + c];
            uint2 v1 = tb[(size_t)i1 * 32 + c];
            ax += bfl(v0.x) + bfl(v1.x);  ay += bfh(v0.x) + bfh(v1.x);
            az += bfl(v0.y) + bfl(v1.y);  aw += bfh(v0.y) + bfh(v1.y);
        }
        if (j < cnt) {
            int i0 = sidx[w][j];
            uint2 v0 = tb[(size_t)i0 * 32 + c];
            ax += bfl(v0.x); ay += bfh(v0.x); az += bfl(v0.y); aw += bfh(v0.y);
        }
    }
    ax += __shfl_xor(ax, 32); ay += __shfl_xor(ay, 32);
    az += __shfl_xor(az, 32); aw += __shfl_xor(aw, 32);
    if (lane < 32) {
        float inv = 1.f / (float)max(e1 - e0, 1);
        float4 bv = ((const float4*)bias)[c];
        float rx = ax * inv + bv.x, ry = ay * inv + bv.y;
        float rz = az * inv + bv.z, rw = aw * inv + bv.w;
        uint2* op = (uint2*)out + (size_t)wid * 32 + c;
        if (ACCUM) {
            uint2 old = *op;
            rx += bfl(old.x); ry += bfh(old.x); rz += bfl(old.y); rw += bfh(old.y);
        }
        *op = make_uint2(pack2(rx, ry), pack2(rz, rw));
    }
}

// D=64: quarter-wave per edge, uint2/lane, unroll 2 -> 8 gathers in flight
template<bool ACCUM>
__global__ __launch_bounds__(256) void agg64_bf16_kernel(const ushort16* __restrict__ t,
                                                         const int* __restrict__ esrc,
                                                         const int* __restrict__ rs,
                                                         const float* __restrict__ bias,
                                                         float* __restrict__ out, int n) {
    __shared__ int sidx[4][64];
    int w = threadIdx.x >> 6;
    int lane = threadIdx.x & 63;
    int wid = blockIdx.x * 4 + w;
    if (wid >= n) return;
    int e0 = rs[wid], e1 = rs[wid + 1];
    int q = lane >> 4, c = lane & 15;
    const uint2* tb = (const uint2*)t;    // row = 16 uint2 (128 B)
    float ax = 0.f, ay = 0.f, az = 0.f, aw = 0.f;
    for (int base = e0; base < e1; base += 64) {
        int cnt = min(64, e1 - base);
        if (lane < cnt) sidx[w][lane] = esrc[base + lane];
        int j = q;
        for (; j + 4 < cnt; j += 8) {
            int i0 = sidx[w][j];
            int i1 = sidx[w][j + 4];
            uint2 v0 = tb[(size_t)i0 * 16 + c];
            uint2 v1 = tb[(size_t)i1 * 16 + c];
            ax += bfl(v0.x) + bfl(v1.x);  ay += bfh(v0.x) + bfh(v1.x);
            az += bfl(v0.y) + bfl(v1.y);  aw += bfh(v0.y) + bfh(v1.y);
        }
        if (j < cnt) {
            int i0 = sidx[w][j];
            uint2 v0 = tb[(size_t)i0 * 16 + c];
            ax += bfl(v0.x); ay += bfh(v0.x); az += bfl(v0.y); aw += bfh(v0.y);
        }
    }
    ax += __shfl_xor(ax, 16); ay += __shfl_xor(ay, 16);
    az += __shfl_xor(az, 16); aw += __shfl_xor(aw, 16);
    ax += __shfl_xor(ax, 32); ay += __shfl_xor(ay, 32);
    az += __shfl_xor(az, 32); aw += __shfl_xor(aw, 32);
    if (lane < 16) {
        float inv = 1.f / (float)max(e1 - e0, 1);
        float4 bv = ((const float4*)bias)[c];
        float4 r;
        r.x = ax * inv + bv.x; r.y = ay * inv + bv.y;
        r.z = az * inv + bv.z; r.w = aw * inv + bv.w;
        float4* op = (float4*)out + (size_t)wid * 16 + c;
        if (ACCUM) { float4 o = *op; r.x += o.x; r.y += o.y; r.z += o.z; r.w += o.w; }
        *op = r;
    }
}

// ---------------- launch ----------------

extern "C" void kernel_launch(void* const* d_in, const int* in_sizes, int n_in,
                              void* d_out, int out_size, void* d_ws, size_t ws_size,
                              hipStream_t stream) {
    const float* x_drug = (const float*)d_in[0];
    const float* x_prot = (const float*)d_in[1];
    const int* src[3] = { (const int*)d_in[2], (const int*)d_in[4], (const int*)d_in[6] };
    const int* dst[3] = { (const int*)d_in[3], (const int*)d_in[5], (const int*)d_in[7] };
    const float* W1[3] = { (const float*)d_in[8],  (const float*)d_in[10], (const float*)d_in[12] };
    const float* b1[3] = { (const float*)d_in[9],  (const float*)d_in[11], (const float*)d_in[13] };
    const float* W2[3] = { (const float*)d_in[14], (const float*)d_in[16], (const float*)d_in[18] };
    const float* b2[3] = { (const float*)d_in[15], (const float*)d_in[17], (const float*)d_in[19] };

    const int ND = in_sizes[0] / 128;
    const int NP = in_sizes[1] / 128;
    const int EC[3] = { in_sizes[2], in_sizes[4], in_sizes[6] };
    float* out = (float*)d_out;

    const int o1 = ND, o2 = ND + NP;
    const int TN = ND + 2 * NP;
    const int e0c = EC[0], e01 = EC[0] + EC[1], e012 = EC[0] + EC[1] + EC[2];
    const int SL = (TN + 7) / 8;            // dst-slice size (8 XCD slices)
    const int NBS = 192;                    // blocks per slice

    // workspace layout
    char* w = (char*)d_ws;
    const size_t maxN = (size_t)(ND > NP ? ND : NP);
    ushort16* xd16 = (ushort16*)w; w += (size_t)ND * 128 * 2;
    ushort16* xp16 = (ushort16*)w; w += (size_t)NP * 128 * 2;
    ushort16* hd16 = (ushort16*)w; w += (size_t)ND * 128 * 2;
    ushort16* hp16 = (ushort16*)w; w += (size_t)NP * 128 * 2;
    ushort16* tb16 = (ushort16*)w; w += maxN * 128 * 2;
    ushort16* Wt[6];
    for (int r = 0; r < 3; ++r) { Wt[r] = (ushort16*)w; w += 128 * 128 * 2; }
    for (int r = 0; r < 3; ++r) { Wt[3 + r] = (ushort16*)w; w += 64 * 128 * 2; }
    int* ip = (int*)w;
    int* deg_all  = ip; ip += TN;
    int* cur_all  = ip; ip += TN;
    const int nzero = 2 * TN;
    int* rs_all   = ip; ip += TN + 1;
    int* esrc_all = ip; ip += e012;
    int* parts    = ip; ip += 256;

    const int* rsr[3] = { rs_all, rs_all + o1, rs_all + o2 };

    // ---- conversions ----
    {
        int n4d = ND * 32, n4p = NP * 32;
        cvt_x2_kernel<<<(n4d + n4p + 255) / 256, 256, 0, stream>>>(x_drug, n4d, x_prot, n4p,
                                                                   (uint32*)xd16, (uint32*)xp16);
        CvtWArgs a;
        for (int r = 0; r < 3; ++r) { a.W[r] = W1[r]; a.W[3 + r] = W2[r]; }
        for (int r = 0; r < 6; ++r) a.Wt[r] = Wt[r];
        cvtW_all_kernel<<<(3 * 16384 + 3 * 8192 + 255) / 256, 256, 0, stream>>>(a);
    }

    // ---- CSR build (XCD-sliced) ----
    zero_int_kernel<<<(nzero + 255) / 256, 256, 0, stream>>>(deg_all, nzero);
    hist_sliced_kernel<<<NBS * 8, 256, 0, stream>>>(dst[0], dst[1], dst[2],
                                                    e0c, e01, e012, o1, o2,
                                                    SL, TN, NBS, deg_all);
    {
        int nb = (TN + SCAN_EPB - 1) / SCAN_EPB;
        scan_partial_kernel<<<nb, SCAN_TPB, 0, stream>>>(deg_all, TN, parts);
        scan_partials_kernel<<<1, 64, 0, stream>>>(parts, nb, rs_all + TN);
        scan_final_kernel<<<nb, SCAN_TPB, 0, stream>>>(deg_all, TN, parts, rs_all);
    }
    scatter_sliced_kernel<<<NBS * 8, 256, 0, stream>>>(src[0], dst[0], src[1], dst[1],
                                                       src[2], dst[2], e0c, e01, e012,
                                                       o1, o2, SL, TN, NBS,
                                                       rs_all, cur_all, esrc_all);

    auto gblocks = [](int n) { return (n + 15) / 16; };
    auto ablocks = [](int n) { return (n + 3) / 4; };

    // ---- layer 1 ----
    gemm_bf16_kernel<128><<<gblocks(ND), 256, 0, stream>>>(xd16, Wt[0], tb16, ND);
    agg128_bf16_kernel<false><<<ablocks(ND), 256, 0, stream>>>(tb16, esrc_all, rsr[0], b1[0],
                                                               (uint32*)hd16, ND);
    gemm_bf16_kernel<128><<<gblocks(ND), 256, 0, stream>>>(xd16, Wt[1], tb16, ND);
    agg128_bf16_kernel<false><<<ablocks(NP), 256, 0, stream>>>(tb16, esrc_all, rsr[1], b1[1],
                                                               (uint32*)hp16, NP);
    gemm_bf16_kernel<128><<<gblocks(NP), 256, 0, stream>>>(xp16, Wt[2], tb16, NP);
    agg128_bf16_kernel<true><<<ablocks(NP), 256, 0, stream>>>(tb16, esrc_all, rsr[2], b1[2],
                                                              (uint32*)hp16, NP);

    // ---- layer 2 ----
    gemm_bf16_kernel<64><<<gblocks(ND), 256, 0, stream>>>(hd16, Wt[3], tb16, ND);
    agg64_bf16_kernel<false><<<ablocks(ND), 256, 0, stream>>>(tb16, esrc_all, rsr[0], b2[0],
                                                              out, ND);
    gemm_bf16_kernel<64><<<gblocks(ND), 256, 0, stream>>>(hd16, Wt[4], tb16, ND);
    agg64_bf16_kernel<false><<<ablocks(NP), 256, 0, stream>>>(tb16, esrc_all, rsr[1], b2[1],
                                                              out + (size_t)ND * 64, NP);
    gemm_bf16_kernel<64><<<gblocks(NP), 256, 0, stream>>>(hp16, Wt[5], tb16, NP);
    agg64_bf16_kernel<true><<<ablocks(NP), 256, 0, stream>>>(tb16, esrc_all, rsr[2], b2[2],
                                                             out + (size_t)ND * 64, NP);
}

// Round 8
// 381.941 us; speedup vs baseline: 2.4937x; 1.2054x over previous
//
#include <hip/hip_runtime.h>

typedef unsigned int uint32;
typedef unsigned short ushort16;
typedef unsigned long long u64;
using short8 = __attribute__((ext_vector_type(8))) short;
using f32x4  = __attribute__((ext_vector_type(4))) float;

__device__ __forceinline__ float bfl(uint32 v) { return __uint_as_float(v << 16); }
__device__ __forceinline__ float bfh(uint32 v) { return __uint_as_float(v & 0xffff0000u); }
__device__ __forceinline__ ushort16 f2bf(float f) {
    uint32 u = __float_as_uint(f);
    u += 0x7fffu + ((u >> 16) & 1u);   // RNE
    return (ushort16)(u >> 16);
}
__device__ __forceinline__ uint32 pack2(float x, float y) {
    return (uint32)f2bf(x) | ((uint32)f2bf(y) << 16);
}

// ---------------- CSR build: LDS-binned two-phase partition ----------------
// Phase A: stage (dst,src) pairs in LDS bins; flush full 256B groups -> full-line writes.
// Phase B: per-bin LDS histogram/scan/scatter -> exact CSR, contiguous per-bin writes.

constexpr int BIN_SH   = 10;     // 1024 nodes per bin
constexpr int CAP_PAIR = 16384;  // global pair capacity per bin (mean ~12.3k, +35 sigma)
constexpr int LCAP     = 48;     // LDS slots per bin
constexpr int NBIN_MAX = 160;    // TN=150k -> 147 bins

__global__ void init_ccur_kernel(int* __restrict__ ccur, int nbin) {
    int b = threadIdx.x;
    if (b < nbin) ccur[b] = b * CAP_PAIR;
}

__global__ __launch_bounds__(256) void part_a_kernel(
        const int* __restrict__ s0, const int* __restrict__ d0,
        const int* __restrict__ s1, const int* __restrict__ d1,
        const int* __restrict__ s2, const int* __restrict__ d2,
        int e0, int e01, int e012, int o1, int o2, int nbin,
        int* __restrict__ ccur, u64* __restrict__ cpair) {
    __shared__ u64 buf[NBIN_MAX][LCAP];
    __shared__ int lcnt[NBIN_MAX];
    const int tid = threadIdx.x;
    for (int b = tid; b < nbin; b += 256) lcnt[b] = 0;
    __syncthreads();
    const int stride = gridDim.x * 256;
    for (int base = blockIdx.x * 256; base < e012; base += stride) {
        int i = base + tid;
        if (i < e012) {
            int g, sv;
            if (i < e0)       { g = d0[i];            sv = s0[i]; }
            else if (i < e01) { g = o1 + d1[i - e0];  sv = s1[i - e0]; }
            else              { g = o2 + d2[i - e01]; sv = s2[i - e01]; }
            int bin = g >> BIN_SH;
            u64 pr = ((u64)(uint32)g << 32) | (uint32)sv;
            int slot = atomicAdd(&lcnt[bin], 1);
            if (slot < LCAP) {
                buf[bin][slot] = pr;
            } else {                       // rare overflow: direct append (correct, slow)
                int p = atomicAdd(&ccur[bin], 1);
                cpair[p] = pr;
                atomicSub(&lcnt[bin], 1);
            }
        }
        __syncthreads();
        if (tid < nbin) {                  // flush full 32-pair (256B) groups
            int cnt = min(lcnt[tid], LCAP);
            if (cnt >= 32) {
                int n = cnt & ~31;
                int p = atomicAdd(&ccur[tid], n);
                for (int k = 0; k < n; ++k) cpair[p + k] = buf[tid][k];
                for (int k = 0; k < cnt - n; ++k) buf[tid][k] = buf[tid][n + k];
                lcnt[tid] = cnt - n;
            }
        }
        __syncthreads();
    }
    if (tid < nbin) {                      // final partial flush
        int cnt = min(lcnt[tid], LCAP);
        if (cnt > 0) {
            int p = atomicAdd(&ccur[tid], cnt);
            for (int k = 0; k < cnt; ++k) cpair[p + k] = buf[tid][k];
        }
    }
}

// exclusive scan of bin counts (counts derived from final cursors); 1 wave
__global__ __launch_bounds__(64) void scan_bins_kernel(const int* __restrict__ ccur, int nbin,
                                                       int* __restrict__ cofs) {
    int lane = threadIdx.x;
    int run = 0;
    for (int base = 0; base < nbin; base += 64) {
        int b = base + lane;
        int c = (b < nbin) ? (ccur[b] - b * CAP_PAIR) : 0;
        int v = c;
        #pragma unroll
        for (int off = 1; off < 64; off <<= 1) {
            int u = __shfl_up(v, off);
            if (lane >= off) v += u;
        }
        if (b < nbin) cofs[b] = run + (v - c);
        run += __shfl(v, 63);
    }
    if (lane == 0) cofs[nbin] = run;
}

// per-bin: LDS deg hist -> LDS scan -> rs write -> LDS-cursor scatter into contiguous esrc
__global__ __launch_bounds__(256) void part_b_kernel(const u64* __restrict__ cpair,
                                                     const int* __restrict__ cofs,
                                                     int nbin, int tn, int e012,
                                                     int* __restrict__ rs,
                                                     int* __restrict__ esrc) {
    __shared__ int rs_l[1024];
    __shared__ int cur_l[1024];
    __shared__ int tsum[256];
    const int bin = blockIdx.x;
    const int t = threadIdx.x;
    const int g0 = bin << BIN_SH;
    const int gcnt = min(1024, tn - g0);
    const int pbase = bin * CAP_PAIR;
    const int obase = cofs[bin];
    const int cnt = cofs[bin + 1] - obase;
    #pragma unroll
    for (int k = 0; k < 4; ++k) cur_l[t + k * 256] = 0;   // deg counters
    __syncthreads();
    for (int i = t; i < cnt; i += 256) {
        int g = (int)(cpair[pbase + i] >> 32);
        atomicAdd(&cur_l[g - g0], 1);
    }
    __syncthreads();
    // exclusive scan of 1024 degs (4 contiguous per thread)
    int v[4]; int s = 0;
    #pragma unroll
    for (int k = 0; k < 4; ++k) { v[k] = cur_l[t * 4 + k]; s += v[k]; }
    tsum[t] = s;
    __syncthreads();
    for (int off = 1; off < 256; off <<= 1) {
        int add = (t >= off) ? tsum[t - off] : 0;
        __syncthreads();
        tsum[t] += add;
        __syncthreads();
    }
    int run = (t ? tsum[t - 1] : 0);
    #pragma unroll
    for (int k = 0; k < 4; ++k) { rs_l[t * 4 + k] = run; run += v[k]; }
    __syncthreads();
    #pragma unroll
    for (int k = 0; k < 4; ++k) {
        int j = t + k * 256;
        if (j < gcnt) rs[g0 + j] = obase + rs_l[j];
    }
    if (bin == nbin - 1 && t == 0) rs[tn] = e012;
    #pragma unroll
    for (int k = 0; k < 4; ++k) cur_l[t + k * 256] = 0;   // now scatter cursors
    __syncthreads();
    for (int i = t; i < cnt; i += 256) {
        u64 pr = cpair[pbase + i];
        int g = (int)(pr >> 32);
        int p = atomicAdd(&cur_l[g - g0], 1);
        esrc[obase + rs_l[g - g0] + p] = (int)(uint32)(pr & 0xffffffffu);
    }
}

// ---------------- conversions (fused) ----------------

__global__ void cvt_x2_kernel(const float* __restrict__ a, int n4a,
                              const float* __restrict__ b, int n4b,
                              uint32* __restrict__ oa, uint32* __restrict__ ob) {
    int i = blockIdx.x * blockDim.x + threadIdx.x;
    if (i < n4a) {
        float4 v = ((const float4*)a)[i];
        ((uint2*)oa)[i] = make_uint2(pack2(v.x, v.y), pack2(v.z, v.w));
    } else if (i < n4a + n4b) {
        int j = i - n4a;
        float4 v = ((const float4*)b)[j];
        ((uint2*)ob)[j] = make_uint2(pack2(v.x, v.y), pack2(v.z, v.w));
    }
}

struct CvtWArgs { const float* W[6]; ushort16* Wt[6]; };

__global__ void cvtW_all_kernel(CvtWArgs a) {
    int i = blockIdx.x * blockDim.x + threadIdx.x;
    if (i < 3 * 16384) {
        int m = i / 16384, idx = i % 16384;
        int n = idx >> 7, k = idx & 127;
        a.Wt[m][n * 128 + k] = f2bf(a.W[m][k * 128 + n]);
    } else {
        i -= 3 * 16384;
        if (i >= 3 * 8192) return;
        int m = 3 + i / 8192, idx = i % 8192;
        int n = idx >> 7, k = idx & 127;
        a.Wt[m][n * 128 + k] = f2bf(a.W[m][k * 64 + n]);
    }
}

// ---------------- MFMA GEMM: Y[N x M](bf16) = X[N x 128](bf16) @ Wt[n][k] ----------------

template<int M>  // 128 or 64
__global__ __launch_bounds__(256) void gemm_bf16_kernel(const ushort16* __restrict__ X,
                                                        const ushort16* __restrict__ Wt,
                                                        ushort16* __restrict__ Y, int N) {
    constexpr int NTW = M / 64;
    const int w = threadIdx.x >> 6;
    const int l = threadIdx.x & 63;
    const int lr = l & 15, lg = l >> 4;
    const int row0 = blockIdx.x * 16;
    if (row0 >= N) return;

    const ushort16* xr = X + (size_t)(row0 + lr) * 128 + lg * 8;
    short8 a[4];
    #pragma unroll
    for (int ks = 0; ks < 4; ++ks) a[ks] = *(const short8*)(xr + ks * 32);

    f32x4 acc[NTW];
    #pragma unroll
    for (int t = 0; t < NTW; ++t) acc[t] = (f32x4){0.f, 0.f, 0.f, 0.f};

    #pragma unroll
    for (int t = 0; t < NTW; ++t) {
        int n = w * (NTW * 16) + t * 16 + lr;
        const ushort16* wr = Wt + (size_t)n * 128 + lg * 8;
        #pragma unroll
        for (int ks = 0; ks < 4; ++ks) {
            short8 b = *(const short8*)(wr + ks * 32);
            acc[t] = __builtin_amdgcn_mfma_f32_16x16x32_bf16(a[ks], b, acc[t], 0, 0, 0);
        }
    }

    #pragma unroll
    for (int t = 0; t < NTW; ++t) {
        int col = w * (NTW * 16) + t * 16 + lr;
        #pragma unroll
        for (int j = 0; j < 4; ++j) {
            int r = row0 + lg * 4 + j;
            Y[(size_t)r * M + col] = f2bf(acc[t][j]);
        }
    }
}

// ---------------- Aggregation (bf16 table, high-MLP, LDS-staged indices) ----------------

// D=128: half-wave per edge, uint2/lane, unroll 2 -> 4 gathers in flight
template<bool ACCUM>
__global__ __launch_bounds__(256) void agg128_bf16_kernel(const ushort16* __restrict__ t,
                                                          const int* __restrict__ esrc,
                                                          const int* __restrict__ rs,
                                                          const float* __restrict__ bias,
                                                          uint32* __restrict__ out, int n) {
    __shared__ int sidx[4][64];
    int w = threadIdx.x >> 6;
    int lane = threadIdx.x & 63;
    int wid = blockIdx.x * 4 + w;
    if (wid >= n) return;
    int e0 = rs[wid], e1 = rs[wid + 1];
    int h = lane >> 5, c = lane & 31;
    const uint2* tb = (const uint2*)t;    // row = 32 uint2 (256 B)
    float ax = 0.f, ay = 0.f, az = 0.f, aw = 0.f;
    for (int base = e0; base < e1; base += 64) {
        int cnt = min(64, e1 - base);
        if (lane < cnt) sidx[w][lane] = esrc[base + lane];  // wave-local: no barrier
        int j = h;
        for (; j + 2 < cnt; j += 4) {
            int i0 = sidx[w][j];
            int i1 = sidx[w][j + 2];
            uint2 v0 = tb[(size_t)i0 * 32 + c];
            uint2 v1 = tb[(size_t)i1 * 32 + c];
            ax += bfl(v0.x) + bfl(v1.x);  ay += bfh(v0.x) + bfh(v1.x);
            az += bfl(v0.y) + bfl(v1.y);  aw += bfh(v0.y) + bfh(v1.y);
        }
        if (j < cnt) {
            int i0 = sidx[w][j];
            uint2 v0 = tb[(size_t)i0 * 32 + c];
            ax += bfl(v0.x); ay += bfh(v0.x); az += bfl(v0.y); aw += bfh(v0.y);
        }
    }
    ax += __shfl_xor(ax, 32); ay += __shfl_xor(ay, 32);
    az += __shfl_xor(az, 32); aw += __shfl_xor(aw, 32);
    if (lane < 32) {
        float inv = 1.f / (float)max(e1 - e0, 1);
        float4 bv = ((const float4*)bias)[c];
        float rx = ax * inv + bv.x, ry = ay * inv + bv.y;
        float rz = az * inv + bv.z, rw = aw * inv + bv.w;
        uint2* op = (uint2*)out + (size_t)wid * 32 + c;
        if (ACCUM) {
            uint2 old = *op;
            rx += bfl(old.x); ry += bfh(old.x); rz += bfl(old.y); rw += bfh(old.y);
        }
        *op = make_uint2(pack2(rx, ry), pack2(rz, rw));
    }
}

// D=64: quarter-wave per edge, uint2/lane, unroll 2 -> 8 gathers in flight
template<bool ACCUM>
__global__ __launch_bounds__(256) void agg64_bf16_kernel(const ushort16* __restrict__ t,
                                                         const int* __restrict__ esrc,
                                                         const int* __restrict__ rs,
                                                         const float* __restrict__ bias,
                                                         float* __restrict__ out, int n) {
    __shared__ int sidx[4][64];
    int w = threadIdx.x >> 6;
    int lane = threadIdx.x & 63;
    int wid = blockIdx.x * 4 + w;
    if (wid >= n) return;
    int e0 = rs[wid], e1 = rs[wid + 1];
    int q = lane >> 4, c = lane & 15;
    const uint2* tb = (const uint2*)t;    // row = 16 uint2 (128 B)
    float ax = 0.f, ay = 0.f, az = 0.f, aw = 0.f;
    for (int base = e0; base < e1; base += 64) {
        int cnt = min(64, e1 - base);
        if (lane < cnt) sidx[w][lane] = esrc[base + lane];
        int j = q;
        for (; j + 4 < cnt; j += 8) {
            int i0 = sidx[w][j];
            int i1 = sidx[w][j + 4];
            uint2 v0 = tb[(size_t)i0 * 16 + c];
            uint2 v1 = tb[(size_t)i1 * 16 + c];
            ax += bfl(v0.x) + bfl(v1.x);  ay += bfh(v0.x) + bfh(v1.x);
            az += bfl(v0.y) + bfl(v1.y);  aw += bfh(v0.y) + bfh(v1.y);
        }
        if (j < cnt) {
            int i0 = sidx[w][j];
            uint2 v0 = tb[(size_t)i0 * 16 + c];
            ax += bfl(v0.x); ay += bfh(v0.x); az += bfl(v0.y); aw += bfh(v0.y);
        }
    }
    ax += __shfl_xor(ax, 16); ay += __shfl_xor(ay, 16);
    az += __shfl_xor(az, 16); aw += __shfl_xor(aw, 16);
    ax += __shfl_xor(ax, 32); ay += __shfl_xor(ay, 32);
    az += __shfl_xor(az, 32); aw += __shfl_xor(aw, 32);
    if (lane < 16) {
        float inv = 1.f / (float)max(e1 - e0, 1);
        float4 bv = ((const float4*)bias)[c];
        float4 r;
        r.x = ax * inv + bv.x; r.y = ay * inv + bv.y;
        r.z = az * inv + bv.z; r.w = aw * inv + bv.w;
        float4* op = (float4*)out + (size_t)wid * 16 + c;
        if (ACCUM) { float4 o = *op; r.x += o.x; r.y += o.y; r.z += o.z; r.w += o.w; }
        *op = r;
    }
}

// ---------------- launch ----------------

extern "C" void kernel_launch(void* const* d_in, const int* in_sizes, int n_in,
                              void* d_out, int out_size, void* d_ws, size_t ws_size,
                              hipStream_t stream) {
    const float* x_drug = (const float*)d_in[0];
    const float* x_prot = (const float*)d_in[1];
    const int* src[3] = { (const int*)d_in[2], (const int*)d_in[4], (const int*)d_in[6] };
    const int* dst[3] = { (const int*)d_in[3], (const int*)d_in[5], (const int*)d_in[7] };
    const float* W1[3] = { (const float*)d_in[8],  (const float*)d_in[10], (const float*)d_in[12] };
    const float* b1[3] = { (const float*)d_in[9],  (const float*)d_in[11], (const float*)d_in[13] };
    const float* W2[3] = { (const float*)d_in[14], (const float*)d_in[16], (const float*)d_in[18] };
    const float* b2[3] = { (const float*)d_in[15], (const float*)d_in[17], (const float*)d_in[19] };

    const int ND = in_sizes[0] / 128;
    const int NP = in_sizes[1] / 128;
    const int EC[3] = { in_sizes[2], in_sizes[4], in_sizes[6] };
    float* out = (float*)d_out;

    const int o1 = ND, o2 = ND + NP;
    const int TN = ND + 2 * NP;
    const int NBIN = (TN + (1 << BIN_SH) - 1) >> BIN_SH;
    const int e0c = EC[0], e01 = EC[0] + EC[1], e012 = EC[0] + EC[1] + EC[2];

    // workspace layout
    char* w = (char*)d_ws;
    const size_t maxN = (size_t)(ND > NP ? ND : NP);
    ushort16* xd16 = (ushort16*)w; w += (size_t)ND * 128 * 2;
    ushort16* xp16 = (ushort16*)w; w += (size_t)NP * 128 * 2;
    ushort16* hd16 = (ushort16*)w; w += (size_t)ND * 128 * 2;
    ushort16* hp16 = (ushort16*)w; w += (size_t)NP * 128 * 2;
    ushort16* tb16 = (ushort16*)w; w += maxN * 128 * 2;
    ushort16* Wt[6];
    for (int r = 0; r < 3; ++r) { Wt[r] = (ushort16*)w; w += 128 * 128 * 2; }
    for (int r = 0; r < 3; ++r) { Wt[3 + r] = (ushort16*)w; w += 64 * 128 * 2; }
    int* ip = (int*)w;
    int* rs_all   = ip; ip += TN + 1;
    int* esrc_all = ip; ip += e012;
    int* ccur     = ip; ip += NBIN_MAX;
    int* cofs     = ip; ip += NBIN_MAX + 1;
    // cpair (19.3 MB) aliases hd16+hp16 (25.6 MB): dead before layer-1 agg writes them
    u64* cpair = (u64*)hd16;

    const int* rsr[3] = { rs_all, rs_all + o1, rs_all + o2 };

    // ---- conversions ----
    {
        int n4d = ND * 32, n4p = NP * 32;
        cvt_x2_kernel<<<(n4d + n4p + 255) / 256, 256, 0, stream>>>(x_drug, n4d, x_prot, n4p,
                                                                   (uint32*)xd16, (uint32*)xp16);
        CvtWArgs a;
        for (int r = 0; r < 3; ++r) { a.W[r] = W1[r]; a.W[3 + r] = W2[r]; }
        for (int r = 0; r < 6; ++r) a.Wt[r] = Wt[r];
        cvtW_all_kernel<<<(3 * 16384 + 3 * 8192 + 255) / 256, 256, 0, stream>>>(a);
    }

    // ---- CSR build (LDS-binned two-phase partition) ----
    init_ccur_kernel<<<1, 256, 0, stream>>>(ccur, NBIN);
    part_a_kernel<<<256, 256, 0, stream>>>(src[0], dst[0], src[1], dst[1], src[2], dst[2],
                                           e0c, e01, e012, o1, o2, NBIN, ccur, cpair);
    scan_bins_kernel<<<1, 64, 0, stream>>>(ccur, NBIN, cofs);
    part_b_kernel<<<NBIN, 256, 0, stream>>>(cpair, cofs, NBIN, TN, e012, rs_all, esrc_all);

    auto gblocks = [](int n) { return (n + 15) / 16; };
    auto ablocks = [](int n) { return (n + 3) / 4; };

    // ---- layer 1 ----
    gemm_bf16_kernel<128><<<gblocks(ND), 256, 0, stream>>>(xd16, Wt[0], tb16, ND);
    agg128_bf16_kernel<false><<<ablocks(ND), 256, 0, stream>>>(tb16, esrc_all, rsr[0], b1[0],
                                                               (uint32*)hd16, ND);
    gemm_bf16_kernel<128><<<gblocks(ND), 256, 0, stream>>>(xd16, Wt[1], tb16, ND);
    agg128_bf16_kernel<false><<<ablocks(NP), 256, 0, stream>>>(tb16, esrc_all, rsr[1], b1[1],
                                                               (uint32*)hp16, NP);
    gemm_bf16_kernel<128><<<gblocks(NP), 256, 0, stream>>>(xp16, Wt[2], tb16, NP);
    agg128_bf16_kernel<true><<<ablocks(NP), 256, 0, stream>>>(tb16, esrc_all, rsr[2], b1[2],
                                                              (uint32*)hp16, NP);

    // ---- layer 2 ----
    gemm_bf16_kernel<64><<<gblocks(ND), 256, 0, stream>>>(hd16, Wt[3], tb16, ND);
    agg64_bf16_kernel<false><<<ablocks(ND), 256, 0, stream>>>(tb16, esrc_all, rsr[0], b2[0],
                                                              out, ND);
    gemm_bf16_kernel<64><<<gblocks(ND), 256, 0, stream>>>(hd16, Wt[4], tb16, ND);
    agg64_bf16_kernel<false><<<ablocks(NP), 256, 0, stream>>>(tb16, esrc_all, rsr[1], b2[1],
                                                              out + (size_t)ND * 64, NP);
    gemm_bf16_kernel<64><<<gblocks(NP), 256, 0, stream>>>(hp16, Wt[5], tb16, NP);
    agg64_bf16_kernel<true><<<ablocks(NP), 256, 0, stream>>>(tb16, esrc_all, rsr[2], b2[2],
                                                             out + (size_t)ND * 64, NP);
}